// Round 7
// baseline (155.090 us; speedup 1.0000x reference)
//
#include <hip/hip_runtime.h>
#include <hip/hip_bf16.h>
#include <stdint.h>

// (B,SQ,SV,D) = (4,4096,4096,64), fp32 in/out.
// Flash attention via bf16 MFMA, 3-term hi/lo split on both matmuls.
// S' = V.Q^T (swapped) so P lands in the PV B-operand layout in-register;
// V row-storage permuted (phi) so P's k-slots are contiguous (v = 8*lg+i).
// Structure (r7): 256 blocks x 256 thr (4 waves). Block = 64 q-rows.
// wave = (qt: 32-q half, half: 2048-key span). 32q/wave amortization (r3's)
// + 2 blocks/CU independence (r6's): LDS = 2 halves x 2 buf x blob = 76 KB.
// One barrier per step; depth-1 prefetch; wave waits only its own loads.
#define BATCH 4
#define SQN   4096
#define SVN   4096
#define DIM   64
#define KT    32               // keys per tile
#define NTILE (SVN / KT)       // 128 tiles per batch
#define NSTEPH 64              // tiles per SV-half (2048/32)

#define RMS 72                 // row-major stride (elems): 144B rows
#define TRS 40                 // transposed stride (elems): 80B rows
#define IMG_RM_H 0
#define IMG_RM_L 4608
#define IMG_TR_H 9216          // RM planes = chunks 0..8
#define IMG_TR_L 14336         // TR planes = chunks 9..18
#define BLOB     19456         // 19 x 1024B chunks
#define LDS_BYTES (4 * BLOB)   // 2 halves x 2 buffers = 77824 B -> 2 blocks/CU

typedef __attribute__((ext_vector_type(8))) short bf16x8;
typedef __attribute__((ext_vector_type(4))) float f32x4;
typedef __attribute__((ext_vector_type(4))) unsigned int u32x4;

#if __has_builtin(__builtin_amdgcn_exp2f)
#define EXP2F __builtin_amdgcn_exp2f
#else
#define EXP2F exp2f
#endif

static __device__ __forceinline__ unsigned short bf16_rne(float x) {
  unsigned u = __float_as_uint(x);
  u += 0x7FFFu + ((u >> 16) & 1u);
  return (unsigned short)(u >> 16);
}
static __device__ __forceinline__ float bf16f(unsigned short h) {
  return __uint_as_float((unsigned)h << 16);
}
static __device__ __forceinline__ unsigned cvt_pk_bf16(float lo, float hi) {
  unsigned r;
  asm("v_cvt_pk_bf16_f32 %0, %1, %2" : "=v"(r) : "v"(lo), "v"(hi));
  return r;
}

// ---------------------------------------------------------------------------
// Prep: V fp32 -> per-tile blobs in ws (unchanged from round 6).
// ---------------------------------------------------------------------------
__global__ __launch_bounds__(256) void vprep_kernel(const float* __restrict__ V,
                                                    char* __restrict__ ws) {
  __shared__ unsigned ex[32][65];
  const int b    = blockIdx.x >> 7;
  const int tile = blockIdx.x & 127;
  const int t    = threadIdx.x;
  const int vv   = t >> 3;
  const int d0   = (t & 7) * 8;

  const float* src = V + (((size_t)b * SVN + (size_t)tile * KT + vv) * DIM + d0);
  const float4 a0 = ((const float4*)src)[0];
  const float4 a1 = ((const float4*)src)[1];
  const float x[8] = {a0.x, a0.y, a0.z, a0.w, a1.x, a1.y, a1.z, a1.w};

  unsigned short h[8], l[8];
#pragma unroll
  for (int j = 0; j < 8; ++j) {
    h[j] = bf16_rne(x[j]);
    l[j] = bf16_rne(x[j] - bf16f(h[j]));
  }

  char* blob = ws + (size_t)(b * NTILE + tile) * BLOB;

  const int p = (((vv >> 2) & 1) << 4) | ((vv >> 3) << 2) | (vv & 3);
  bf16x8 vh, vl;
#pragma unroll
  for (int j = 0; j < 8; ++j) { vh[j] = (short)h[j]; vl[j] = (short)l[j]; }
  *(bf16x8*)(blob + IMG_RM_H + (p * RMS + d0) * 2) = vh;
  *(bf16x8*)(blob + IMG_RM_L + (p * RMS + d0) * 2) = vl;

#pragma unroll
  for (int j = 0; j < 8; ++j) ex[vv][d0 + j] = (unsigned)h[j] | ((unsigned)l[j] << 16);
  __syncthreads();

  const int r  = t >> 1;
  const int pl = r >> 6;
  const int d  = r & 63;
  const int hh = t & 1;
  unsigned w16[16];
#pragma unroll
  for (int c = 0; c < 16; ++c) w16[c] = ex[hh * 16 + c][d];
  u32x4 o0, o1;
#pragma unroll
  for (int k = 0; k < 8; ++k) {
    const unsigned w0 = w16[2 * k], w1 = w16[2 * k + 1];
    const unsigned dw = pl ? ((w0 >> 16) | (w1 & 0xFFFF0000u))
                           : ((w0 & 0xFFFFu) | (w1 << 16));
    if (k < 4) o0[k] = dw; else o1[k - 4] = dw;
  }
  char* dst = blob + (pl ? IMG_TR_L : IMG_TR_H) + (d * TRS + hh * 16) * 2;
  ((u32x4*)dst)[0] = o0;
  ((u32x4*)dst)[1] = o1;
}

// ---------------------------------------------------------------------------
// Main: 256 blocks x 256 thr. Block = 64 q-rows of one batch.
// wave w: qt = w&1 (32-q half), half = w>>1 (2048-key span). 2-way merge.
// ---------------------------------------------------------------------------
__global__ __launch_bounds__(256, 2) void attn_kernel(const float* __restrict__ Qg,
                                                      const char* __restrict__ vprep,
                                                      float* __restrict__ out) {
  extern __shared__ char smem[];
  const int raw = blockIdx.x;
  const int lb = (raw & 7) * 32 + (raw >> 3);  // XCD swizzle (256 % 8 == 0)
  const int batch = lb >> 6;
  const int qbase = (lb & 63) * 64;
  const int tid = threadIdx.x;
  const int lane = tid & 63;
  const int wid = tid >> 6;
  const int qt = wid & 1;
  const int half = wid >> 1;
  const int lr = lane & 15;
  const int lg = lane >> 4;

  // ---- Q fragments (x log2e), hi/lo split; B slot (lg,j) <-> d = ks*32+8lg+j
  bf16x8 Qh[2][2], Ql[2][2];
#pragma unroll
  for (int qb = 0; qb < 2; ++qb) {
    const size_t qrow = (size_t)batch * SQN + qbase + qt * 32 + qb * 16 + lr;
#pragma unroll
    for (int ks = 0; ks < 2; ++ks) {
      const float* qp = Qg + qrow * DIM + ks * 32 + 8 * lg;
      const float4 f0 = ((const float4*)qp)[0];
      const float4 f1 = ((const float4*)qp)[1];
      const float xv[8] = {f0.x, f0.y, f0.z, f0.w, f1.x, f1.y, f1.z, f1.w};
#pragma unroll
      for (int j = 0; j < 8; ++j) {
        const float v = xv[j] * 1.44269504088896f;
        const unsigned short hh = bf16_rne(v);
        Qh[qb][ks][j] = (short)hh;
        Ql[qb][ks][j] = (short)bf16_rne(v - bf16f(hh));
      }
    }
  }

  f32x4 Oacc[2][4];
#pragma unroll
  for (int qb = 0; qb < 2; ++qb)
#pragma unroll
    for (int db = 0; db < 4; ++db) Oacc[qb][db] = (f32x4){0.f, 0.f, 0.f, 0.f};
  float m_[2] = {-1e30f, -1e30f};
  float l_[2] = {0.f, 0.f};

  const size_t tb0 = (size_t)(batch * NTILE) * BLOB;

  // per step each wave stages 10 of the 19 chunks (qt0: 0-9, qt1: 9-18; dup 9)
  auto stage = [&](int t, int b) {
    const size_t g0 = tb0 + (size_t)(half * NSTEPH + t) * BLOB;
    char* l0 = smem + (half * 2 + b) * BLOB;
    const int c0 = qt * 9;
#pragma unroll
    for (int k = 0; k < 10; ++k) {
      const int sub = c0 + k;
      __builtin_amdgcn_global_load_lds(
          (const __attribute__((address_space(1))) unsigned int*)(vprep + g0 + sub * 1024 + lane * 16),
          (__attribute__((address_space(3))) unsigned int*)(l0 + sub * 1024), 16, 0, 0);
    }
  };

  stage(0, 0);
  int buf = 0;

  for (int t = 0; t < NSTEPH; ++t) {
    // own 10 loads for tile t were issued a full step ago -> cheap drain
    asm volatile("s_waitcnt vmcnt(0)" ::: "memory");
    __builtin_amdgcn_s_barrier();
    if (t + 1 < NSTEPH) stage(t + 1, buf ^ 1);

    const char* qbuf = smem + (half * 2 + buf) * BLOB;

    // ---- all LDS reads for this tile up front (TR feeds PV after softmax;
    //      having it in regs removes LDS latency from the softmax->PV chain)
    bf16x8 Vh[2][2], Vl[2][2];
#pragma unroll
    for (int vt = 0; vt < 2; ++vt)
#pragma unroll
      for (int ks = 0; ks < 2; ++ks) {
        const int off = ((vt * 16 + lr) * RMS + ks * 32 + 8 * lg) * 2;
        Vh[vt][ks] = *(const bf16x8*)(qbuf + IMG_RM_H + off);
        Vl[vt][ks] = *(const bf16x8*)(qbuf + IMG_RM_L + off);
      }
    bf16x8 Ah[4], Al[4];
#pragma unroll
    for (int db = 0; db < 4; ++db) {
      const int toff = ((db * 16 + lr) * TRS + 8 * lg) * 2;
      Ah[db] = *(const bf16x8*)(qbuf + IMG_TR_H + toff);
      Al[db] = *(const bf16x8*)(qbuf + IMG_TR_L + toff);
    }

    // ---- phase A: S' = V.Q^T (3-term) -----------------------------------
    f32x4 sacc[2][2];
    __builtin_amdgcn_s_setprio(1);
#pragma unroll
    for (int qb = 0; qb < 2; ++qb)
#pragma unroll
      for (int vt = 0; vt < 2; ++vt) {
        f32x4 acc = (f32x4){0.f, 0.f, 0.f, 0.f};
#pragma unroll
        for (int ks = 0; ks < 2; ++ks) {
          acc = __builtin_amdgcn_mfma_f32_16x16x32_bf16(Vh[vt][ks], Qh[qb][ks], acc, 0, 0, 0);
          acc = __builtin_amdgcn_mfma_f32_16x16x32_bf16(Vh[vt][ks], Ql[qb][ks], acc, 0, 0, 0);
          acc = __builtin_amdgcn_mfma_f32_16x16x32_bf16(Vl[vt][ks], Qh[qb][ks], acc, 0, 0, 0);
        }
        sacc[qb][vt] = acc;
      }
    __builtin_amdgcn_s_setprio(0);

    // ---- online softmax (log2 domain); p[i] <-> v = 8lg+i = PV B k-slot --
    bf16x8 Ph[2], Pl[2];
#pragma unroll
    for (int qb = 0; qb < 2; ++qb) {
      float mt = -1e30f;
#pragma unroll
      for (int vt = 0; vt < 2; ++vt)
#pragma unroll
        for (int r = 0; r < 4; ++r) mt = fmaxf(mt, sacc[qb][vt][r]);
      mt = fmaxf(mt, __shfl_xor(mt, 16, 64));
      mt = fmaxf(mt, __shfl_xor(mt, 32, 64));

      float p[8];
      float rs = 0.f;
      if (__any(mt > m_[qb] + 8.0f)) {
        const float mnew = fmaxf(m_[qb], mt);
        const float alpha = EXP2F(m_[qb] - mnew);
#pragma unroll
        for (int vt = 0; vt < 2; ++vt)
#pragma unroll
          for (int r = 0; r < 4; ++r) {
            const float pv = EXP2F(sacc[qb][vt][r] - mnew);
            p[vt * 4 + r] = pv;
            rs += pv;
          }
        rs += __shfl_xor(rs, 16, 64);
        rs += __shfl_xor(rs, 32, 64);
        l_[qb] = l_[qb] * alpha + rs;
        m_[qb] = mnew;
#pragma unroll
        for (int db = 0; db < 4; ++db) Oacc[qb][db] *= alpha;
      } else {
        // deferred (T13): keep old max; P bounded by 2^8
#pragma unroll
        for (int vt = 0; vt < 2; ++vt)
#pragma unroll
          for (int r = 0; r < 4; ++r) {
            const float pv = EXP2F(sacc[qb][vt][r] - m_[qb]);
            p[vt * 4 + r] = pv;
            rs += pv;
          }
        rs += __shfl_xor(rs, 16, 64);
        rs += __shfl_xor(rs, 32, 64);
        l_[qb] += rs;
      }

      u32x4 hu, lu;
#pragma unroll
      for (int j = 0; j < 4; ++j) {
        const unsigned hd = cvt_pk_bf16(p[2 * j], p[2 * j + 1]);
        const float h0 = __uint_as_float(hd << 16);
        const float h1 = __uint_as_float(hd & 0xFFFF0000u);
        hu[j] = hd;
        lu[j] = cvt_pk_bf16(p[2 * j] - h0, p[2 * j + 1] - h1);
      }
      Ph[qb] = __builtin_bit_cast(bf16x8, hu);
      Pl[qb] = __builtin_bit_cast(bf16x8, lu);
    }

    // ---- phase B: PV — A slot (lg,i) = V[8lg+i][d], operands in regs -----
    __builtin_amdgcn_s_setprio(1);
#pragma unroll
    for (int db = 0; db < 4; ++db)
#pragma unroll
      for (int qb = 0; qb < 2; ++qb) {
        Oacc[qb][db] = __builtin_amdgcn_mfma_f32_16x16x32_bf16(Ah[db], Ph[qb], Oacc[qb][db], 0, 0, 0);
        Oacc[qb][db] = __builtin_amdgcn_mfma_f32_16x16x32_bf16(Al[db], Ph[qb], Oacc[qb][db], 0, 0, 0);
        Oacc[qb][db] = __builtin_amdgcn_mfma_f32_16x16x32_bf16(Ah[db], Pl[qb], Oacc[qb][db], 0, 0, 0);
      }
    __builtin_amdgcn_s_setprio(0);

    buf ^= 1;
  }

  __syncthreads();  // loop fully drained; safe to reuse smem for merge

  // ---- 2-way half merge through LDS ----
  float* mbuf = (float*)smem;                       // [2 half][64 q][68]
  float* mlb  = (float*)(smem + 2 * 64 * 68 * 4);   // [2 half][64 q][2]
#pragma unroll
  for (int qb = 0; qb < 2; ++qb) {
    const int ridx = half * 64 + qt * 32 + qb * 16 + lr;
    float* dst = mbuf + ridx * 68;
#pragma unroll
    for (int db = 0; db < 4; ++db)
#pragma unroll
      for (int r = 0; r < 4; ++r) dst[db * 16 + 4 * lg + r] = Oacc[qb][db][r];
    if (lg == 0) {
      mlb[ridx * 2 + 0] = m_[qb];
      mlb[ridx * 2 + 1] = l_[qb];
    }
  }
  __syncthreads();

  const int qh = tid >> 3;          // 0..31
  const int d0 = (tid & 7) * 8;
#pragma unroll
  for (int rep = 0; rep < 2; ++rep) {
    const int q = rep * 32 + qh;    // 0..63
    const float M = fmaxf(mlb[q * 2], mlb[(64 + q) * 2]);
    float L = 0.f;
    float o[8] = {0, 0, 0, 0, 0, 0, 0, 0};
#pragma unroll
    for (int hf = 0; hf < 2; ++hf) {
      const int ridx = hf * 64 + q;
      const float a = EXP2F(mlb[ridx * 2] - M);
      L += a * mlb[ridx * 2 + 1];
      const float* srcp = mbuf + ridx * 68 + d0;
#pragma unroll
      for (int j = 0; j < 8; ++j) o[j] += a * srcp[j];
    }
    const float inv = 1.0f / L;
    float* op = out + ((size_t)batch * SQN + qbase + q) * DIM + d0;
    float4 w0 = {o[0] * inv, o[1] * inv, o[2] * inv, o[3] * inv};
    float4 w1 = {o[4] * inv, o[5] * inv, o[6] * inv, o[7] * inv};
    ((float4*)op)[0] = w0;
    ((float4*)op)[1] = w1;
  }
}

// ---------------------------------------------------------------------------
extern "C" void kernel_launch(void* const* d_in, const int* in_sizes, int n_in,
                              void* d_out, int out_size, void* d_ws, size_t ws_size,
                              hipStream_t stream) {
  const float* Qg = (const float*)d_in[0];
  const float* Vg = (const float*)d_in[1];
  float* out = (float*)d_out;
  char* ws = (char*)d_ws;
  const size_t need = (size_t)BATCH * NTILE * BLOB;  // 9.96 MB
  if (ws_size < need) return;

  hipFuncSetAttribute((const void*)attn_kernel,
                      hipFuncAttributeMaxDynamicSharedMemorySize, LDS_BYTES);

  vprep_kernel<<<BATCH * NTILE, 256, 0, stream>>>(Vg, ws);
  attn_kernel<<<256, 256, LDS_BYTES, stream>>>(Qg, ws, out);
}

// Round 8
// 140.438 us; speedup vs baseline: 1.1043x; 1.1043x over previous
//
#include <hip/hip_runtime.h>
#include <hip/hip_bf16.h>
#include <stdint.h>

// (B,SQ,SV,D) = (4,4096,4096,64), fp32 in/out.
// Flash attention via bf16 MFMA, 3-term hi/lo split on both matmuls.
// S' = V.Q^T (swapped) so P lands in the PV B-operand layout in-register;
// V row-storage permuted (phi) so P's k-slots are contiguous (v = 8*lg+i).
// r8: 512 blocks x 256 thr (4 waves). Block = 64 q-rows x 2048-key SV-half
// (svh). wave = (qt: 32-q half, half: 1024-key span). LDS 76KB -> 2 blocks/CU
// = 8 waves/CU = 2 waves/SIMD in TWO independent barrier domains.
// Cross-block svh merge via partials in ws + merge kernel (fallback: SPLIT=1).
#define BATCH 4
#define SQN   4096
#define SVN   4096
#define DIM   64
#define KT    32               // keys per tile
#define NTILE (SVN / KT)       // 128 tiles per batch

#define RMS 72                 // row-major stride (elems): 144B rows
#define TRS 40                 // transposed stride (elems): 80B rows
#define IMG_RM_H 0
#define IMG_RM_L 4608
#define IMG_TR_H 9216          // RM planes = chunks 0..8
#define IMG_TR_L 14336         // TR planes = chunks 9..18
#define BLOB     19456         // 19 x 1024B chunks
#define LDS_BYTES (4 * BLOB)   // 2 spans x 2 buffers = 77824 B -> 2 blocks/CU

#define BLOB_BYTES ((size_t)BATCH * NTILE * BLOB)          // 9,961,472
#define PARTO_ELEMS ((size_t)512 * 64 * 64)                // per-slot 64q x 64d
#define PARTML_ELEMS ((size_t)512 * 64 * 2)

typedef __attribute__((ext_vector_type(8))) short bf16x8;
typedef __attribute__((ext_vector_type(4))) float f32x4;
typedef __attribute__((ext_vector_type(4))) unsigned int u32x4;

#if __has_builtin(__builtin_amdgcn_exp2f)
#define EXP2F __builtin_amdgcn_exp2f
#else
#define EXP2F exp2f
#endif

static __device__ __forceinline__ unsigned short bf16_rne(float x) {
  unsigned u = __float_as_uint(x);
  u += 0x7FFFu + ((u >> 16) & 1u);
  return (unsigned short)(u >> 16);
}
static __device__ __forceinline__ float bf16f(unsigned short h) {
  return __uint_as_float((unsigned)h << 16);
}
static __device__ __forceinline__ unsigned cvt_pk_bf16(float lo, float hi) {
  unsigned r;
  asm("v_cvt_pk_bf16_f32 %0, %1, %2" : "=v"(r) : "v"(lo), "v"(hi));
  return r;
}

// ---------------------------------------------------------------------------
// Prep: V fp32 -> per-tile blobs in ws (unchanged from round 6/7).
// ---------------------------------------------------------------------------
__global__ __launch_bounds__(256) void vprep_kernel(const float* __restrict__ V,
                                                    char* __restrict__ ws) {
  __shared__ unsigned ex[32][65];
  const int b    = blockIdx.x >> 7;
  const int tile = blockIdx.x & 127;
  const int t    = threadIdx.x;
  const int vv   = t >> 3;
  const int d0   = (t & 7) * 8;

  const float* src = V + (((size_t)b * SVN + (size_t)tile * KT + vv) * DIM + d0);
  const float4 a0 = ((const float4*)src)[0];
  const float4 a1 = ((const float4*)src)[1];
  const float x[8] = {a0.x, a0.y, a0.z, a0.w, a1.x, a1.y, a1.z, a1.w};

  unsigned short h[8], l[8];
#pragma unroll
  for (int j = 0; j < 8; ++j) {
    h[j] = bf16_rne(x[j]);
    l[j] = bf16_rne(x[j] - bf16f(h[j]));
  }

  char* blob = ws + (size_t)(b * NTILE + tile) * BLOB;

  const int p = (((vv >> 2) & 1) << 4) | ((vv >> 3) << 2) | (vv & 3);
  bf16x8 vh, vl;
#pragma unroll
  for (int j = 0; j < 8; ++j) { vh[j] = (short)h[j]; vl[j] = (short)l[j]; }
  *(bf16x8*)(blob + IMG_RM_H + (p * RMS + d0) * 2) = vh;
  *(bf16x8*)(blob + IMG_RM_L + (p * RMS + d0) * 2) = vl;

#pragma unroll
  for (int j = 0; j < 8; ++j) ex[vv][d0 + j] = (unsigned)h[j] | ((unsigned)l[j] << 16);
  __syncthreads();

  const int r  = t >> 1;
  const int pl = r >> 6;
  const int d  = r & 63;
  const int hh = t & 1;
  unsigned w16[16];
#pragma unroll
  for (int c = 0; c < 16; ++c) w16[c] = ex[hh * 16 + c][d];
  u32x4 o0, o1;
#pragma unroll
  for (int k = 0; k < 8; ++k) {
    const unsigned w0 = w16[2 * k], w1 = w16[2 * k + 1];
    const unsigned dw = pl ? ((w0 >> 16) | (w1 & 0xFFFF0000u))
                           : ((w0 & 0xFFFFu) | (w1 << 16));
    if (k < 4) o0[k] = dw; else o1[k - 4] = dw;
  }
  char* dst = blob + (pl ? IMG_TR_L : IMG_TR_H) + (d * TRS + hh * 16) * 2;
  ((u32x4*)dst)[0] = o0;
  ((u32x4*)dst)[1] = o1;
}

// ---------------------------------------------------------------------------
// Main. SPLIT=2: 512 blocks, block = (batch, qblock, svh); xcd = batch*2+svh
// so each XCD's L2 caches one 2048-key span's blobs (1.24 MB).
// SPLIT=1: 256 blocks, full SV per block (fallback when ws too small).
// ---------------------------------------------------------------------------
template <int SPLIT>
__global__ __launch_bounds__(256, 2) void attn_kernel(const float* __restrict__ Qg,
                                                      const char* __restrict__ vprep,
                                                      float* __restrict__ partO,
                                                      float* __restrict__ partML,
                                                      float* __restrict__ out) {
  constexpr int NSTEP = (SPLIT == 2) ? 32 : 64;  // tiles per wave-span
  extern __shared__ char smem[];
  const int raw = blockIdx.x;
  int batch, qblock, svh;
  if constexpr (SPLIT == 2) {
    batch = (raw & 7) >> 1; svh = raw & 1; qblock = raw >> 3;
  } else {
    const int lb = (raw & 7) * 32 + (raw >> 3);
    batch = lb >> 6; qblock = lb & 63; svh = 0;
  }
  const int qbase = qblock * 64;
  const int tid = threadIdx.x;
  const int lane = tid & 63;
  const int wid = tid >> 6;
  const int qt = wid & 1;
  const int half = wid >> 1;
  const int lr = lane & 15;
  const int lg = lane >> 4;

  // ---- Q fragments (x log2e), hi/lo split; B slot (lg,j) <-> d = ks*32+8lg+j
  bf16x8 Qh[2][2], Ql[2][2];
#pragma unroll
  for (int qb = 0; qb < 2; ++qb) {
    const size_t qrow = (size_t)batch * SQN + qbase + qt * 32 + qb * 16 + lr;
#pragma unroll
    for (int ks = 0; ks < 2; ++ks) {
      const float* qp = Qg + qrow * DIM + ks * 32 + 8 * lg;
      const float4 f0 = ((const float4*)qp)[0];
      const float4 f1 = ((const float4*)qp)[1];
      const float xv[8] = {f0.x, f0.y, f0.z, f0.w, f1.x, f1.y, f1.z, f1.w};
#pragma unroll
      for (int j = 0; j < 8; ++j) {
        const float v = xv[j] * 1.44269504088896f;
        const unsigned short hh = bf16_rne(v);
        Qh[qb][ks][j] = (short)hh;
        Ql[qb][ks][j] = (short)bf16_rne(v - bf16f(hh));
      }
    }
  }

  f32x4 Oacc[2][4];
#pragma unroll
  for (int qb = 0; qb < 2; ++qb)
#pragma unroll
    for (int db = 0; db < 4; ++db) Oacc[qb][db] = (f32x4){0.f, 0.f, 0.f, 0.f};
  float m_[2] = {-1e30f, -1e30f};
  float l_[2] = {0.f, 0.f};

  const size_t tb0 = (size_t)(batch * NTILE) * BLOB;
  const int tile0 = svh * 64 + half * NSTEP;

  // per step each wave stages 10 of the 19 chunks (qt0: 0-9, qt1: 9-18; dup 9)
  auto stage = [&](int t, int b) {
    const size_t g0 = tb0 + (size_t)(tile0 + t) * BLOB;
    char* l0 = smem + (half * 2 + b) * BLOB;
    const int c0 = qt * 9;
#pragma unroll
    for (int k = 0; k < 10; ++k) {
      const int sub = c0 + k;
      __builtin_amdgcn_global_load_lds(
          (const __attribute__((address_space(1))) unsigned int*)(vprep + g0 + sub * 1024 + lane * 16),
          (__attribute__((address_space(3))) unsigned int*)(l0 + sub * 1024), 16, 0, 0);
    }
  };

  stage(0, 0);
  int buf = 0;

  for (int t = 0; t < NSTEP; ++t) {
    asm volatile("s_waitcnt vmcnt(0)" ::: "memory");
    __builtin_amdgcn_s_barrier();
    if (t + 1 < NSTEP) stage(t + 1, buf ^ 1);

    const char* qbuf = smem + (half * 2 + buf) * BLOB;

    // all LDS reads up front (TR hoisted out of the softmax->PV chain)
    bf16x8 Vh[2][2], Vl[2][2];
#pragma unroll
    for (int vt = 0; vt < 2; ++vt)
#pragma unroll
      for (int ks = 0; ks < 2; ++ks) {
        const int off = ((vt * 16 + lr) * RMS + ks * 32 + 8 * lg) * 2;
        Vh[vt][ks] = *(const bf16x8*)(qbuf + IMG_RM_H + off);
        Vl[vt][ks] = *(const bf16x8*)(qbuf + IMG_RM_L + off);
      }
    bf16x8 Ah[4], Al[4];
#pragma unroll
    for (int db = 0; db < 4; ++db) {
      const int toff = ((db * 16 + lr) * TRS + 8 * lg) * 2;
      Ah[db] = *(const bf16x8*)(qbuf + IMG_TR_H + toff);
      Al[db] = *(const bf16x8*)(qbuf + IMG_TR_L + toff);
    }

    // ---- phase A: S' = V.Q^T (3-term) -----------------------------------
    f32x4 sacc[2][2];
    __builtin_amdgcn_s_setprio(1);
#pragma unroll
    for (int qb = 0; qb < 2; ++qb)
#pragma unroll
      for (int vt = 0; vt < 2; ++vt) {
        f32x4 acc = (f32x4){0.f, 0.f, 0.f, 0.f};
#pragma unroll
        for (int ks = 0; ks < 2; ++ks) {
          acc = __builtin_amdgcn_mfma_f32_16x16x32_bf16(Vh[vt][ks], Qh[qb][ks], acc, 0, 0, 0);
          acc = __builtin_amdgcn_mfma_f32_16x16x32_bf16(Vh[vt][ks], Ql[qb][ks], acc, 0, 0, 0);
          acc = __builtin_amdgcn_mfma_f32_16x16x32_bf16(Vl[vt][ks], Qh[qb][ks], acc, 0, 0, 0);
        }
        sacc[qb][vt] = acc;
      }
    __builtin_amdgcn_s_setprio(0);

    // ---- online softmax (log2 domain); p[i] <-> v = 8lg+i = PV B k-slot --
    bf16x8 Ph[2], Pl[2];
#pragma unroll
    for (int qb = 0; qb < 2; ++qb) {
      float mt = -1e30f;
#pragma unroll
      for (int vt = 0; vt < 2; ++vt)
#pragma unroll
        for (int r = 0; r < 4; ++r) mt = fmaxf(mt, sacc[qb][vt][r]);
      mt = fmaxf(mt, __shfl_xor(mt, 16, 64));
      mt = fmaxf(mt, __shfl_xor(mt, 32, 64));

      float p[8];
      float rs = 0.f;
      if (__any(mt > m_[qb] + 8.0f)) {
        const float mnew = fmaxf(m_[qb], mt);
        const float alpha = EXP2F(m_[qb] - mnew);
#pragma unroll
        for (int vt = 0; vt < 2; ++vt)
#pragma unroll
          for (int r = 0; r < 4; ++r) {
            const float pv = EXP2F(sacc[qb][vt][r] - mnew);
            p[vt * 4 + r] = pv;
            rs += pv;
          }
        rs += __shfl_xor(rs, 16, 64);
        rs += __shfl_xor(rs, 32, 64);
        l_[qb] = l_[qb] * alpha + rs;
        m_[qb] = mnew;
#pragma unroll
        for (int db = 0; db < 4; ++db) Oacc[qb][db] *= alpha;
      } else {
        // deferred (T13): keep old max; P bounded by 2^8
#pragma unroll
        for (int vt = 0; vt < 2; ++vt)
#pragma unroll
          for (int r = 0; r < 4; ++r) {
            const float pv = EXP2F(sacc[qb][vt][r] - m_[qb]);
            p[vt * 4 + r] = pv;
            rs += pv;
          }
        rs += __shfl_xor(rs, 16, 64);
        rs += __shfl_xor(rs, 32, 64);
        l_[qb] += rs;
      }

      u32x4 hu, lu;
#pragma unroll
      for (int j = 0; j < 4; ++j) {
        const unsigned hd = cvt_pk_bf16(p[2 * j], p[2 * j + 1]);
        const float h0 = __uint_as_float(hd << 16);
        const float h1 = __uint_as_float(hd & 0xFFFF0000u);
        hu[j] = hd;
        lu[j] = cvt_pk_bf16(p[2 * j] - h0, p[2 * j + 1] - h1);
      }
      Ph[qb] = __builtin_bit_cast(bf16x8, hu);
      Pl[qb] = __builtin_bit_cast(bf16x8, lu);
    }

    // ---- phase B: PV — operands already in regs --------------------------
    __builtin_amdgcn_s_setprio(1);
#pragma unroll
    for (int db = 0; db < 4; ++db)
#pragma unroll
      for (int qb = 0; qb < 2; ++qb) {
        Oacc[qb][db] = __builtin_amdgcn_mfma_f32_16x16x32_bf16(Ah[db], Ph[qb], Oacc[qb][db], 0, 0, 0);
        Oacc[qb][db] = __builtin_amdgcn_mfma_f32_16x16x32_bf16(Al[db], Ph[qb], Oacc[qb][db], 0, 0, 0);
        Oacc[qb][db] = __builtin_amdgcn_mfma_f32_16x16x32_bf16(Ah[db], Pl[qb], Oacc[qb][db], 0, 0, 0);
      }
    __builtin_amdgcn_s_setprio(0);

    buf ^= 1;
  }

  __syncthreads();  // loop fully drained; safe to reuse smem for merge

  // ---- 2-way span merge through LDS ----
  float* mbuf = (float*)smem;                       // [2 span][64 q][68]
  float* mlb  = (float*)(smem + 2 * 64 * 68 * 4);   // [2 span][64 q][2]
#pragma unroll
  for (int qb = 0; qb < 2; ++qb) {
    const int ridx = half * 64 + qt * 32 + qb * 16 + lr;
    float* dst = mbuf + ridx * 68;
#pragma unroll
    for (int db = 0; db < 4; ++db)
#pragma unroll
      for (int r = 0; r < 4; ++r) dst[db * 16 + 4 * lg + r] = Oacc[qb][db][r];
    if (lg == 0) {
      mlb[ridx * 2 + 0] = m_[qb];
      mlb[ridx * 2 + 1] = l_[qb];
    }
  }
  __syncthreads();

  const int qh = tid >> 3;          // 0..31
  const int d0 = (tid & 7) * 8;
#pragma unroll
  for (int rep = 0; rep < 2; ++rep) {
    const int q = rep * 32 + qh;    // 0..63
    const float M = fmaxf(mlb[q * 2], mlb[(64 + q) * 2]);
    float L = 0.f;
    float o[8] = {0, 0, 0, 0, 0, 0, 0, 0};
#pragma unroll
    for (int hf = 0; hf < 2; ++hf) {
      const int ridx = hf * 64 + q;
      const float a = EXP2F(mlb[ridx * 2] - M);
      L += a * mlb[ridx * 2 + 1];
      const float* srcp = mbuf + ridx * 68 + d0;
#pragma unroll
      for (int j = 0; j < 8; ++j) o[j] += a * srcp[j];
    }
    if constexpr (SPLIT == 1) {
      const float inv = 1.0f / L;
      float* op = out + ((size_t)batch * SQN + qbase + q) * DIM + d0;
      float4 w0 = {o[0] * inv, o[1] * inv, o[2] * inv, o[3] * inv};
      float4 w1 = {o[4] * inv, o[5] * inv, o[6] * inv, o[7] * inv};
      ((float4*)op)[0] = w0;
      ((float4*)op)[1] = w1;
    } else {
      // partial: unnormalized numerator (scale 2^M) + (M, L)
      const int pslot = (batch * 64 + qblock) * 2 + svh;
      float* po = partO + ((size_t)pslot * 64 + q) * 64 + d0;
      float4 w0 = {o[0], o[1], o[2], o[3]};
      float4 w1 = {o[4], o[5], o[6], o[7]};
      ((float4*)po)[0] = w0;
      ((float4*)po)[1] = w1;
      if (d0 == 0) {
        partML[((size_t)pslot * 64 + q) * 2 + 0] = M;
        partML[((size_t)pslot * 64 + q) * 2 + 1] = L;
      }
    }
  }
}

// ---------------------------------------------------------------------------
// Merge: combine the two svh partials per q-row. 512 blocks x 256 thr.
// ---------------------------------------------------------------------------
__global__ __launch_bounds__(256) void merge_kernel(const float* __restrict__ partO,
                                                    const float* __restrict__ partML,
                                                    float* __restrict__ out) {
  const int gidx = blockIdx.x * 256 + threadIdx.x;  // 0..131071
  const int pq = gidx >> 3;        // global q-row 0..16383
  const int d0 = (gidx & 7) * 8;
  const int batch = pq >> 12;
  const int qb = (pq >> 6) & 63;
  const int qr = pq & 63;
  const int slot0 = (batch * 64 + qb) * 2;

  const float m0 = partML[((size_t)slot0 * 64 + qr) * 2 + 0];
  const float l0 = partML[((size_t)slot0 * 64 + qr) * 2 + 1];
  const float m1 = partML[((size_t)(slot0 + 1) * 64 + qr) * 2 + 0];
  const float l1 = partML[((size_t)(slot0 + 1) * 64 + qr) * 2 + 1];
  const float M = fmaxf(m0, m1);
  const float a0 = EXP2F(m0 - M);
  const float a1 = EXP2F(m1 - M);
  const float inv = 1.0f / (a0 * l0 + a1 * l1);

  const float* p0 = partO + ((size_t)slot0 * 64 + qr) * 64 + d0;
  const float* p1 = partO + ((size_t)(slot0 + 1) * 64 + qr) * 64 + d0;
  const float4 x0 = ((const float4*)p0)[0];
  const float4 x1 = ((const float4*)p0)[1];
  const float4 y0 = ((const float4*)p1)[0];
  const float4 y1 = ((const float4*)p1)[1];
  float4 w0 = {(a0 * x0.x + a1 * y0.x) * inv, (a0 * x0.y + a1 * y0.y) * inv,
               (a0 * x0.z + a1 * y0.z) * inv, (a0 * x0.w + a1 * y0.w) * inv};
  float4 w1 = {(a0 * x1.x + a1 * y1.x) * inv, (a0 * x1.y + a1 * y1.y) * inv,
               (a0 * x1.z + a1 * y1.z) * inv, (a0 * x1.w + a1 * y1.w) * inv};
  float* op = out + (size_t)pq * DIM + d0;
  ((float4*)op)[0] = w0;
  ((float4*)op)[1] = w1;
}

// ---------------------------------------------------------------------------
extern "C" void kernel_launch(void* const* d_in, const int* in_sizes, int n_in,
                              void* d_out, int out_size, void* d_ws, size_t ws_size,
                              hipStream_t stream) {
  const float* Qg = (const float*)d_in[0];
  const float* Vg = (const float*)d_in[1];
  float* out = (float*)d_out;
  char* ws = (char*)d_ws;

  const size_t need1 = BLOB_BYTES;                                   // 9.96 MB
  const size_t need2 = BLOB_BYTES + (PARTO_ELEMS + PARTML_ELEMS) * 4; // ~18.7 MB
  if (ws_size < need1) return;

  vprep_kernel<<<BATCH * NTILE, 256, 0, stream>>>(Vg, ws);

  if (ws_size >= need2) {
    float* partO  = (float*)(ws + BLOB_BYTES);
    float* partML = partO + PARTO_ELEMS;
    hipFuncSetAttribute((const void*)attn_kernel<2>,
                        hipFuncAttributeMaxDynamicSharedMemorySize, LDS_BYTES);
    attn_kernel<2><<<512, 256, LDS_BYTES, stream>>>(Qg, ws, partO, partML, out);
    merge_kernel<<<512, 256, 0, stream>>>(partO, partML, out);
  } else {
    hipFuncSetAttribute((const void*)attn_kernel<1>,
                        hipFuncAttributeMaxDynamicSharedMemorySize, LDS_BYTES);
    attn_kernel<1><<<256, 256, LDS_BYTES, stream>>>(Qg, ws, nullptr, nullptr, out);
  }
}